// Round 1
// baseline (287.245 us; speedup 1.0000x reference)
//
#include <hip/hip_runtime.h>
#include <hip/hip_bf16.h>
#include <hip/hip_fp16.h>

typedef _Float16 h8_t __attribute__((ext_vector_type(8)));
typedef _Float16 h4_t __attribute__((ext_vector_type(4)));
typedef float f4_t __attribute__((ext_vector_type(4)));

#define M_ROWS 32768

__device__ __forceinline__ void gload_lds16(const void* g, void* l) {
  __builtin_amdgcn_global_load_lds((const __attribute__((address_space(1))) void*)g,
                                   (__attribute__((address_space(3))) void*)l, 16, 0, 0);
}

__device__ __forceinline__ float sigmoid_f(float x) { return 1.f / (1.f + __expf(-x)); }
// robust tanh: x->+inf gives 1-0=1, x->-inf gives 1-2=-1 (no inf/inf NaN)
__device__ __forceinline__ float tanh_f(float x) { return 1.f - 2.f / (__expf(2.f * x) + 1.f); }

__global__ void cvt_f32_f16(const float* __restrict__ s, _Float16* __restrict__ d, int n) {
  int i = blockIdx.x * blockDim.x + threadIdx.x;
  int i4 = i * 4;
  if (i4 >= n) return;
  float4 v = *(const float4*)(s + i4);
  h4_t o;
  o[0] = (_Float16)v.x; o[1] = (_Float16)v.y; o[2] = (_Float16)v.z; o[3] = (_Float16)v.w;
  *(h4_t*)(d + i4) = o;
}

// colsum of aff_W (10x512) + sum(aff_b) -> wsum[0..511], wsum[512]=bias sum
__global__ void prep_wsum(const float* __restrict__ aff_W, const float* __restrict__ aff_b,
                          float* __restrict__ wsum) {
  int j = threadIdx.x;  // 512
  float s = 0.f;
#pragma unroll
  for (int r = 0; r < 10; ++r) s += aff_W[r * 512 + j];
  wsum[j] = s;
  if (j == 0) {
    float bs = 0.f;
#pragma unroll
    for (int r = 0; r < 10; ++r) bs += aff_b[r];
    wsum[512] = bs;
  }
}

__global__ void zero2(float* __restrict__ pg, float* __restrict__ pn) {
  int i = blockIdx.x * blockDim.x + threadIdx.x;
  pg[i] = 0.f;
  pn[i] = 0.f;
}

// One fused LSTM layer: pre = A @ Wih.T + b for gates {i,g,o} (f skipped: c0=0),
// h = sigmoid(o)*tanh(sigmoid(i)*tanh(g)).
// !FUSE: write h (fp16) to Hout (M x H row-major).
// FUSE:  h = relu(h); atomicAdd per-row dot(h, rvec) into partial (layer-2 epilogue fusion).
template <int K_DIM, int H_DIM, bool FUSE>
__global__ __launch_bounds__(256, 2) void lstm_gemm(
    const _Float16* __restrict__ A,    // M x K_DIM fp16 row-major
    const _Float16* __restrict__ W,    // 4H x K_DIM fp16 row-major (torch Wih layout)
    const float* __restrict__ bias,    // 4H fp32
    _Float16* __restrict__ Hout,       // M x H fp16 (if !FUSE)
    const float* __restrict__ rvec,    // H fp32 reduction weights (if FUSE)
    float* __restrict__ partial) {     // M fp32 (if FUSE)
  __shared__ __align__(16) _Float16 As[128 * 64];      // 16 KB [m][k]
  __shared__ __align__(16) _Float16 Bs[3 * 64 * 64];   // 24 KB [gate][j][k]

  const int tid = threadIdx.x;
  const int wid = tid >> 6;
  const int lane = tid & 63;
  const int wave_m = wid >> 1;   // 0..1
  const int wave_h = wid & 1;    // 0..1
  const int q = lane >> 4;       // quad 0..3
  const int tcol = lane & 15;

  const int m0 = blockIdx.x * 128;
  const int h0 = blockIdx.y * 64;

  f4_t acc[3][4][2];
#pragma unroll
  for (int p = 0; p < 3; ++p)
#pragma unroll
    for (int mi = 0; mi < 4; ++mi)
#pragma unroll
      for (int ni = 0; ni < 2; ++ni) acc[p][mi][ni] = (f4_t){0.f, 0.f, 0.f, 0.f};

  for (int k0 = 0; k0 < K_DIM; k0 += 64) {
    // ---- stage A tile (128x64 fp16 = 16KB = 16 x 1KB wave-chunks) ----
#pragma unroll
    for (int c = 0; c < 4; ++c) {
      int o = ((wid * 4 + c) << 10) + (lane << 4);  // byte offset in As
      int row = o >> 7;                             // 128B per row
      int kel = (o & 127) >> 1;
      gload_lds16(A + (size_t)(m0 + row) * K_DIM + k0 + kel, (char*)As + o);
    }
    // ---- stage B tiles: 3 gate panels x (64x64) = 24KB = 24 chunks ----
#pragma unroll
    for (int c = 0; c < 6; ++c) {
      int o = ((wid * 6 + c) << 10) + (lane << 4);
      int p = o >> 13;         // panel (8KB each)
      int oo = o & 8191;
      int j = oo >> 7;
      int kel = (oo & 127) >> 1;
      int grow = (p == 0 ? 0 : (p == 1 ? 2 * H_DIM : 3 * H_DIM)) + h0 + j;
      gload_lds16(W + (size_t)grow * K_DIM + k0 + kel, (char*)Bs + o);
    }
    __syncthreads();  // drains vmcnt(0) -> LDS valid

#pragma unroll
    for (int ks = 0; ks < 2; ++ks) {
      h8_t af[4];
#pragma unroll
      for (int mi = 0; mi < 4; ++mi)
        af[mi] = *(const h8_t*)&As[(wave_m * 64 + mi * 16 + tcol) * 64 + ks * 32 + q * 8];
#pragma unroll
      for (int p = 0; p < 3; ++p) {
#pragma unroll
        for (int ni = 0; ni < 2; ++ni) {
          h8_t bf = *(const h8_t*)&Bs[p * 4096 + (wave_h * 32 + ni * 16 + tcol) * 64 + ks * 32 + q * 8];
#pragma unroll
          for (int mi = 0; mi < 4; ++mi)
            acc[p][mi][ni] = __builtin_amdgcn_mfma_f32_16x16x32_f16(af[mi], bf, acc[p][mi][ni], 0, 0, 0);
        }
      }
    }
    __syncthreads();  // before next stage overwrites LDS
  }

  // ---- epilogue ----
  const int mrow0 = m0 + wave_m * 64;
  const int jcol0 = h0 + wave_h * 32;

  if constexpr (!FUSE) {
#pragma unroll
    for (int ni = 0; ni < 2; ++ni) {
      int j = jcol0 + ni * 16 + tcol;
      float bi = bias[j];
      float bg = bias[2 * H_DIM + j];
      float bo = bias[3 * H_DIM + j];
#pragma unroll
      for (int mi = 0; mi < 4; ++mi) {
#pragma unroll
        for (int r = 0; r < 4; ++r) {
          float pi = acc[0][mi][ni][r] + bi;
          float pgt = acc[1][mi][ni][r] + bg;
          float po = acc[2][mi][ni][r] + bo;
          float cc = sigmoid_f(pi) * tanh_f(pgt);
          float hh = sigmoid_f(po) * tanh_f(cc);
          int m = mrow0 + mi * 16 + q * 4 + r;
          Hout[(size_t)m * H_DIM + j] = (_Float16)hh;
        }
      }
    }
  } else {
    float rsum[4][4];
#pragma unroll
    for (int mi = 0; mi < 4; ++mi)
#pragma unroll
      for (int r = 0; r < 4; ++r) rsum[mi][r] = 0.f;
#pragma unroll
    for (int ni = 0; ni < 2; ++ni) {
      int j = jcol0 + ni * 16 + tcol;
      float bi = bias[j];
      float bg = bias[2 * H_DIM + j];
      float bo = bias[3 * H_DIM + j];
      float rv = rvec[j];
#pragma unroll
      for (int mi = 0; mi < 4; ++mi) {
#pragma unroll
        for (int r = 0; r < 4; ++r) {
          float pi = acc[0][mi][ni][r] + bi;
          float pgt = acc[1][mi][ni][r] + bg;
          float po = acc[2][mi][ni][r] + bo;
          float cc = sigmoid_f(pi) * tanh_f(pgt);
          float hh = sigmoid_f(po) * tanh_f(cc);
          hh = fmaxf(hh, 0.f);  // relu on layer-2 output
          rsum[mi][r] += hh * rv;
        }
      }
    }
#pragma unroll
    for (int mi = 0; mi < 4; ++mi) {
#pragma unroll
      for (int r = 0; r < 4; ++r) {
        float v = rsum[mi][r];
        v += __shfl_xor(v, 1);
        v += __shfl_xor(v, 2);
        v += __shfl_xor(v, 4);
        v += __shfl_xor(v, 8);
        if (tcol == 0) atomicAdd(&partial[mrow0 + mi * 16 + q * 4 + r], v);
      }
    }
  }
}

__global__ void finalize(const float* __restrict__ pg, const float* __restrict__ pn,
                         const float* __restrict__ wsum, const float* __restrict__ noise_b,
                         float* __restrict__ out) {
  int i = blockIdx.x * blockDim.x + threadIdx.x;  // 32768
  out[i] = pg[i] + wsum[512];
  float x = pn[i] + noise_b[0];
  float sp = fmaxf(x, 0.f) + log1pf(expf(-fabsf(x)));  // stable softplus
  out[M_ROWS + i] = sp + 1e-6f;
}

extern "C" void kernel_launch(void* const* d_in, const int* in_sizes, int n_in,
                              void* d_out, int out_size, void* d_ws, size_t ws_size,
                              hipStream_t stream) {
  const float* X       = (const float*)d_in[0];
  const float* g_Wih0  = (const float*)d_in[1];
  const float* g_b0    = (const float*)d_in[2];
  const float* g_Wih1  = (const float*)d_in[3];
  const float* g_b1    = (const float*)d_in[4];
  const float* aff_W   = (const float*)d_in[5];
  const float* aff_b   = (const float*)d_in[6];
  const float* n_Wih0  = (const float*)d_in[7];
  const float* n_b0    = (const float*)d_in[8];
  const float* n_Wih1  = (const float*)d_in[9];
  const float* n_b1    = (const float*)d_in[10];
  const float* noise_W = (const float*)d_in[11];
  const float* noise_b = (const float*)d_in[12];
  float* out = (float*)d_out;

  char* w = (char*)d_ws;
  _Float16* Xh  = (_Float16*)w; w += (size_t)M_ROWS * 128 * 2;  // 8 MB
  _Float16* Wg0 = (_Float16*)w; w += 2048 * 128 * 2;
  _Float16* Wg1 = (_Float16*)w; w += 2048 * 512 * 2;
  _Float16* Wn0 = (_Float16*)w; w += 1024 * 128 * 2;
  _Float16* Wn1 = (_Float16*)w; w += 1024 * 256 * 2;
  _Float16* h1g = (_Float16*)w; w += (size_t)M_ROWS * 512 * 2;  // 32 MB
  _Float16* h1n = (_Float16*)w; w += (size_t)M_ROWS * 256 * 2;  // 16 MB
  float* pg   = (float*)w; w += (size_t)M_ROWS * 4;
  float* pn   = (float*)w; w += (size_t)M_ROWS * 4;
  float* wsum = (float*)w; w += 4096;

  auto cvt = [&](const float* s, _Float16* d, int n) {
    cvt_f32_f16<<<(n / 4 + 255) / 256, 256, 0, stream>>>(s, d, n);
  };
  cvt(X, Xh, M_ROWS * 128);
  cvt(g_Wih0, Wg0, 2048 * 128);
  cvt(g_Wih1, Wg1, 2048 * 512);
  cvt(n_Wih0, Wn0, 1024 * 128);
  cvt(n_Wih1, Wn1, 1024 * 256);
  prep_wsum<<<1, 512, 0, stream>>>(aff_W, aff_b, wsum);
  zero2<<<M_ROWS / 256, 256, 0, stream>>>(pg, pn);

  // layer 1 (both branches read Xh)
  lstm_gemm<128, 512, false><<<dim3(M_ROWS / 128, 8), 256, 0, stream>>>(Xh, Wg0, g_b0, h1g, nullptr, nullptr);
  lstm_gemm<128, 256, false><<<dim3(M_ROWS / 128, 4), 256, 0, stream>>>(Xh, Wn0, n_b0, h1n, nullptr, nullptr);
  // layer 2 with fused relu + row-dot reduction (h2 never materialized)
  lstm_gemm<512, 512, true><<<dim3(M_ROWS / 128, 8), 256, 0, stream>>>(h1g, Wg1, g_b1, nullptr, wsum, pg);
  lstm_gemm<256, 256, true><<<dim3(M_ROWS / 128, 4), 256, 0, stream>>>(h1n, Wn1, n_b1, nullptr, noise_W, pn);

  finalize<<<M_ROWS / 256, 256, 0, stream>>>(pg, pn, wsum, noise_b, out);
}

// Round 2
// 262.775 us; speedup vs baseline: 1.0931x; 1.0931x over previous
//
#include <hip/hip_runtime.h>
#include <hip/hip_bf16.h>
#include <hip/hip_fp16.h>

typedef _Float16 h8_t __attribute__((ext_vector_type(8)));
typedef _Float16 h4_t __attribute__((ext_vector_type(4)));
typedef float f4_t __attribute__((ext_vector_type(4)));

#define M_ROWS 32768

__device__ __forceinline__ void gload_lds16(const void* g, void* l) {
  __builtin_amdgcn_global_load_lds((const __attribute__((address_space(1))) void*)g,
                                   (__attribute__((address_space(3))) void*)l, 16, 0, 0);
}

__device__ __forceinline__ float sigmoid_f(float x) { return 1.f / (1.f + __expf(-x)); }
__device__ __forceinline__ float tanh_f(float x) { return 1.f - 2.f / (__expf(2.f * x) + 1.f); }

struct GArgs {
  const _Float16* A;   // M x K fp16
  const _Float16* W;   // 4H x K fp16
  const float* bias;   // 4H
  _Float16* Hout;      // M x H (layer-1)
  const float* rvec;   // H (layer-2 fused reduction weights)
  float* partial;      // M (layer-2 fused output)
};

// ---- fused prep: all fp32->fp16 converts + zero partials + aff colsum ----
// region block ranges (256 thr, 4 elems/thr for cvt):
//   [0,4096)      X      4194304 el
//   [4096,4352)   g_Wih0  262144
//   [4352,5376)   g_Wih1 1048576
//   [5376,5504)   n_Wih0  131072
//   [5504,5760)   n_Wih1  262144
//   [5760,5888)   zero pg/pn (1 el/thr each)
//   [5888,5890)   wsum (512 cols)
__global__ void prep_all(const float* __restrict__ X, const float* __restrict__ gW0,
                         const float* __restrict__ gW1, const float* __restrict__ nW0,
                         const float* __restrict__ nW1, const float* __restrict__ aff_W,
                         const float* __restrict__ aff_b,
                         _Float16* __restrict__ Xh, _Float16* __restrict__ Wg0,
                         _Float16* __restrict__ Wg1, _Float16* __restrict__ Wn0,
                         _Float16* __restrict__ Wn1,
                         float* __restrict__ pg, float* __restrict__ pn,
                         float* __restrict__ wsum) {
  int b = blockIdx.x;
  const float* s; _Float16* d; int base;
  if (b < 4096)      { s = X;   d = Xh;  base = b; }
  else if (b < 4352) { s = gW0; d = Wg0; base = b - 4096; }
  else if (b < 5376) { s = gW1; d = Wg1; base = b - 4352; }
  else if (b < 5504) { s = nW0; d = Wn0; base = b - 5376; }
  else if (b < 5760) { s = nW1; d = Wn1; base = b - 5504; }
  else if (b < 5888) {
    int i = (b - 5760) * 256 + threadIdx.x;
    pg[i] = 0.f; pn[i] = 0.f;
    return;
  } else {
    int j = (b - 5888) * 256 + threadIdx.x;  // 0..511
    float sum = 0.f;
#pragma unroll
    for (int r = 0; r < 10; ++r) sum += aff_W[r * 512 + j];
    wsum[j] = sum;
    if (j == 0) {
      float bs = 0.f;
#pragma unroll
      for (int r = 0; r < 10; ++r) bs += aff_b[r];
      wsum[512] = bs;
    }
    return;
  }
  int i4 = (base * 256 + threadIdx.x) * 4;
  float4 v = *(const float4*)(s + i4);
  h4_t o;
  o[0] = (_Float16)v.x; o[1] = (_Float16)v.y; o[2] = (_Float16)v.z; o[3] = (_Float16)v.w;
  *(h4_t*)(d + i4) = o;
}

// ---- core GEMM body: pre = A@W.T (+bias) for gates {i,g,o}, LSTM-step0 epilogue.
// XOR-swizzled LDS (chunk c of row r stored at chunk c^(r&7)), hoisted staging
// pointers (+64 elems/iter), hoisted LDS read offsets.
template <int K_DIM, int H_DIM, bool FUSE>
__device__ __forceinline__ void gemm_body(const GArgs& ga, int h0,
                                          _Float16* As, _Float16* Bs) {
  const int tid = threadIdx.x;
  const int wid = tid >> 6;
  const int lane = tid & 63;
  const int wave_m = wid >> 1;
  const int wave_h = wid & 1;
  const int q = lane >> 4;
  const int tcol = lane & 15;
  const int m0 = blockIdx.x * 128;

  // staging pointers/offsets (A: 4 chunks, B: 6 chunks of 1KB)
  const _Float16* aptr[4]; int aoff[4];
#pragma unroll
  for (int c = 0; c < 4; ++c) {
    int o = ((wid * 4 + c) << 10) + (lane << 4);
    int row = o >> 7, pch = (o >> 4) & 7;
    int lch = pch ^ (row & 7);
    aptr[c] = ga.A + (size_t)(m0 + row) * K_DIM + lch * 8;
    aoff[c] = o;
  }
  const _Float16* bptr[6]; int boff[6];
#pragma unroll
  for (int c = 0; c < 6; ++c) {
    int o = ((wid * 6 + c) << 10) + (lane << 4);
    int pan = o >> 13;
    int row = (o >> 7) & 63, pch = (o >> 4) & 7;
    int lch = pch ^ (row & 7);
    int gbase = (pan == 0 ? 0 : (pan == 1 ? 2 * H_DIM : 3 * H_DIM)) + h0 + row;
    bptr[c] = ga.W + (size_t)gbase * K_DIM + lch * 8;
    boff[c] = o;
  }
  // LDS read offsets (k-invariant, elements)
  int a_rd[2][4];
#pragma unroll
  for (int ks = 0; ks < 2; ++ks)
#pragma unroll
    for (int mi = 0; mi < 4; ++mi) {
      int r = wave_m * 64 + mi * 16 + tcol;
      int c = ks * 4 + q;
      a_rd[ks][mi] = r * 64 + (c ^ (r & 7)) * 8;
    }
  int b_rd[2][2];
#pragma unroll
  for (int ks = 0; ks < 2; ++ks)
#pragma unroll
    for (int ni = 0; ni < 2; ++ni) {
      int j = wave_h * 32 + ni * 16 + tcol;
      int c = ks * 4 + q;
      b_rd[ks][ni] = j * 64 + (c ^ (j & 7)) * 8;
    }

  f4_t acc[3][4][2];
#pragma unroll
  for (int p = 0; p < 3; ++p)
#pragma unroll
    for (int mi = 0; mi < 4; ++mi)
#pragma unroll
      for (int ni = 0; ni < 2; ++ni) acc[p][mi][ni] = (f4_t){0.f, 0.f, 0.f, 0.f};

#pragma unroll
  for (int kk = 0; kk < K_DIM / 64; ++kk) {
#pragma unroll
    for (int c = 0; c < 4; ++c) gload_lds16(aptr[c], (char*)As + aoff[c]);
#pragma unroll
    for (int c = 0; c < 6; ++c) gload_lds16(bptr[c], (char*)Bs + boff[c]);
#pragma unroll
    for (int c = 0; c < 4; ++c) aptr[c] += 64;
#pragma unroll
    for (int c = 0; c < 6; ++c) bptr[c] += 64;
    __syncthreads();  // vmcnt(0) drain -> LDS valid

#pragma unroll
    for (int ks = 0; ks < 2; ++ks) {
      h8_t af[4];
#pragma unroll
      for (int mi = 0; mi < 4; ++mi) af[mi] = *(const h8_t*)&As[a_rd[ks][mi]];
#pragma unroll
      for (int p = 0; p < 3; ++p) {
#pragma unroll
        for (int ni = 0; ni < 2; ++ni) {
          h8_t bf = *(const h8_t*)&Bs[p * 4096 + b_rd[ks][ni]];
#pragma unroll
          for (int mi = 0; mi < 4; ++mi)
            acc[p][mi][ni] = __builtin_amdgcn_mfma_f32_16x16x32_f16(af[mi], bf, acc[p][mi][ni], 0, 0, 0);
        }
      }
    }
    __syncthreads();
  }

  const int mrow0 = m0 + wave_m * 64;
  const int jcol0 = h0 + wave_h * 32;

  if constexpr (!FUSE) {
#pragma unroll
    for (int ni = 0; ni < 2; ++ni) {
      int j = jcol0 + ni * 16 + tcol;
      float bi = ga.bias[j];
      float bg = ga.bias[2 * H_DIM + j];
      float bo = ga.bias[3 * H_DIM + j];
#pragma unroll
      for (int mi = 0; mi < 4; ++mi)
#pragma unroll
        for (int r = 0; r < 4; ++r) {
          float pi = acc[0][mi][ni][r] + bi;
          float pgt = acc[1][mi][ni][r] + bg;
          float po = acc[2][mi][ni][r] + bo;
          float cc = sigmoid_f(pi) * tanh_f(pgt);
          float hh = sigmoid_f(po) * tanh_f(cc);
          int m = mrow0 + mi * 16 + q * 4 + r;
          ga.Hout[(size_t)m * H_DIM + j] = (_Float16)hh;
        }
    }
  } else {
    float rsum[4][4];
#pragma unroll
    for (int mi = 0; mi < 4; ++mi)
#pragma unroll
      for (int r = 0; r < 4; ++r) rsum[mi][r] = 0.f;
#pragma unroll
    for (int ni = 0; ni < 2; ++ni) {
      int j = jcol0 + ni * 16 + tcol;
      float bi = ga.bias[j];
      float bg = ga.bias[2 * H_DIM + j];
      float bo = ga.bias[3 * H_DIM + j];
      float rv = ga.rvec[j];
#pragma unroll
      for (int mi = 0; mi < 4; ++mi)
#pragma unroll
        for (int r = 0; r < 4; ++r) {
          float pi = acc[0][mi][ni][r] + bi;
          float pgt = acc[1][mi][ni][r] + bg;
          float po = acc[2][mi][ni][r] + bo;
          float cc = sigmoid_f(pi) * tanh_f(pgt);
          float hh = sigmoid_f(po) * tanh_f(cc);
          hh = fmaxf(hh, 0.f);
          rsum[mi][r] += hh * rv;
        }
    }
#pragma unroll
    for (int mi = 0; mi < 4; ++mi)
#pragma unroll
      for (int r = 0; r < 4; ++r) {
        float v = rsum[mi][r];
        v += __shfl_xor(v, 1);
        v += __shfl_xor(v, 2);
        v += __shfl_xor(v, 4);
        v += __shfl_xor(v, 8);
        if (tcol == 0) atomicAdd(&ga.partial[mrow0 + mi * 16 + q * 4 + r], v);
      }
  }
}

// layer-1 (both branches, K=128): grid (256, 12); y<8 -> global(H=512), else noise(H=256)
__global__ __launch_bounds__(256, 2) void layer1_fused(GArgs g, GArgs n) {
  __shared__ __align__(16) _Float16 As[128 * 64];
  __shared__ __align__(16) _Float16 Bs[3 * 64 * 64];
  int y = blockIdx.y;
  if (y < 8) gemm_body<128, 512, false>(g, y * 64, As, Bs);
  else       gemm_body<128, 256, false>(n, (y - 8) * 64, As, Bs);
}

// layer-2 (both branches, fused relu+row-dot): y<8 -> global(K=512), else noise(K=256)
__global__ __launch_bounds__(256, 2) void layer2_fused(GArgs g, GArgs n) {
  __shared__ __align__(16) _Float16 As[128 * 64];
  __shared__ __align__(16) _Float16 Bs[3 * 64 * 64];
  int y = blockIdx.y;
  if (y < 8) gemm_body<512, 512, true>(g, y * 64, As, Bs);
  else       gemm_body<256, 256, true>(n, (y - 8) * 64, As, Bs);
}

__global__ void finalize(const float* __restrict__ pg, const float* __restrict__ pn,
                         const float* __restrict__ wsum, const float* __restrict__ noise_b,
                         float* __restrict__ out) {
  int i = blockIdx.x * blockDim.x + threadIdx.x;
  out[i] = pg[i] + wsum[512];
  float x = pn[i] + noise_b[0];
  float sp = fmaxf(x, 0.f) + log1pf(expf(-fabsf(x)));
  out[M_ROWS + i] = sp + 1e-6f;
}

extern "C" void kernel_launch(void* const* d_in, const int* in_sizes, int n_in,
                              void* d_out, int out_size, void* d_ws, size_t ws_size,
                              hipStream_t stream) {
  const float* X       = (const float*)d_in[0];
  const float* g_Wih0  = (const float*)d_in[1];
  const float* g_b0    = (const float*)d_in[2];
  const float* g_Wih1  = (const float*)d_in[3];
  const float* g_b1    = (const float*)d_in[4];
  const float* aff_W   = (const float*)d_in[5];
  const float* aff_b   = (const float*)d_in[6];
  const float* n_Wih0  = (const float*)d_in[7];
  const float* n_b0    = (const float*)d_in[8];
  const float* n_Wih1  = (const float*)d_in[9];
  const float* n_b1    = (const float*)d_in[10];
  const float* noise_W = (const float*)d_in[11];
  const float* noise_b = (const float*)d_in[12];
  float* out = (float*)d_out;

  char* w = (char*)d_ws;
  _Float16* Xh  = (_Float16*)w; w += (size_t)M_ROWS * 128 * 2;
  _Float16* Wg0 = (_Float16*)w; w += 2048 * 128 * 2;
  _Float16* Wg1 = (_Float16*)w; w += 2048 * 512 * 2;
  _Float16* Wn0 = (_Float16*)w; w += 1024 * 128 * 2;
  _Float16* Wn1 = (_Float16*)w; w += 1024 * 256 * 2;
  _Float16* h1g = (_Float16*)w; w += (size_t)M_ROWS * 512 * 2;
  _Float16* h1n = (_Float16*)w; w += (size_t)M_ROWS * 256 * 2;
  float* pg   = (float*)w; w += (size_t)M_ROWS * 4;
  float* pn   = (float*)w; w += (size_t)M_ROWS * 4;
  float* wsum = (float*)w; w += 4096;

  prep_all<<<5890, 256, 0, stream>>>(X, g_Wih0, g_Wih1, n_Wih0, n_Wih1, aff_W, aff_b,
                                     Xh, Wg0, Wg1, Wn0, Wn1, pg, pn, wsum);

  GArgs l1g = {Xh, Wg0, g_b0, h1g, nullptr, nullptr};
  GArgs l1n = {Xh, Wn0, n_b0, h1n, nullptr, nullptr};
  layer1_fused<<<dim3(M_ROWS / 128, 12), 256, 0, stream>>>(l1g, l1n);

  GArgs l2g = {h1g, Wg1, g_b1, nullptr, wsum, pg};
  GArgs l2n = {h1n, Wn1, n_b1, nullptr, noise_W, pn};
  layer2_fused<<<dim3(M_ROWS / 128, 12), 256, 0, stream>>>(l2g, l2n);

  finalize<<<M_ROWS / 256, 256, 0, stream>>>(pg, pn, wsum, noise_b, out);
}